// Round 1
// baseline (1491.462 us; speedup 1.0000x reference)
//
#include <hip/hip_runtime.h>

// Problem dims (fixed by setup_inputs)
#define T_  4
#define B_  8
#define N_  1024
#define BN_ 8192      // B_*N_
#define D_  512
#define H_  2048

// Tiling
#define BM  64        // rows (bn) per block
#define BNT 64        // cols per block
#define BK  16
#define PAD 68        // BM + 4 pad, multiple of 4 for aligned float4

typedef float f4 __attribute__((ext_vector_type(4)));

// ---------------- Kernel 1: h = x @ W1^T  (NT gemm), fused PLIF scan over T,
// ---------------- write s1 spikes as u8 into workspace.
__global__ __launch_bounds__(256)
void k_fc1_scan(const float* __restrict__ x, const float* __restrict__ W1,
                const float* __restrict__ alpha1p, unsigned char* __restrict__ s1)
{
    __shared__ float As[T_][BK][PAD];
    __shared__ float Bs[BK][PAD];

    const int tid = threadIdx.x;
    const int bn0 = blockIdx.x * BM;
    const int h0  = blockIdx.y * BNT;
    const int tx  = tid & 15, ty = tid >> 4;
    const int i0  = ty * 4, j0 = tx * 4;
    const int srow = tid >> 2;   // 0..63
    const int sseg = tid & 3;    // 0..3  -> k offset sseg*4

    float acc[T_][4][4];
#pragma unroll
    for (int t = 0; t < T_; ++t)
#pragma unroll
        for (int i = 0; i < 4; ++i)
#pragma unroll
            for (int j = 0; j < 4; ++j) acc[t][i][j] = 0.f;

    for (int k0 = 0; k0 < D_; k0 += BK) {
        // stage A tiles (one per timestep), transposed into [k][row]
#pragma unroll
        for (int t = 0; t < T_; ++t) {
            const f4 av = *reinterpret_cast<const f4*>(
                &x[(size_t)((t * BN_) + bn0 + srow) * D_ + k0 + sseg * 4]);
            As[t][sseg * 4 + 0][srow] = av[0];
            As[t][sseg * 4 + 1][srow] = av[1];
            As[t][sseg * 4 + 2][srow] = av[2];
            As[t][sseg * 4 + 3][srow] = av[3];
        }
        {
            const f4 bv = *reinterpret_cast<const f4*>(
                &W1[(size_t)(h0 + srow) * D_ + k0 + sseg * 4]);
            Bs[sseg * 4 + 0][srow] = bv[0];
            Bs[sseg * 4 + 1][srow] = bv[1];
            Bs[sseg * 4 + 2][srow] = bv[2];
            Bs[sseg * 4 + 3][srow] = bv[3];
        }
        __syncthreads();

#pragma unroll
        for (int kk = 0; kk < BK; ++kk) {
            const f4 b = *reinterpret_cast<const f4*>(&Bs[kk][j0]);
#pragma unroll
            for (int t = 0; t < T_; ++t) {
                const f4 a = *reinterpret_cast<const f4*>(&As[t][kk][i0]);
#pragma unroll
                for (int i = 0; i < 4; ++i)
#pragma unroll
                    for (int j = 0; j < 4; ++j)
                        acc[t][i][j] = fmaf(a[i], b[j], acc[t][i][j]);
            }
        }
        __syncthreads();
    }

    // PLIF scan over T (per output element), hard reset, write u8 spikes
    const float a1 = alpha1p[0];
#pragma unroll
    for (int i = 0; i < 4; ++i) {
        float v[4] = {0.f, 0.f, 0.f, 0.f};
#pragma unroll
        for (int t = 0; t < T_; ++t) {
            uchar4 sv;
            unsigned char* svp = &sv.x;
#pragma unroll
            for (int j = 0; j < 4; ++j) {
                v[j] = v[j] + a1 * (acc[t][i][j] - v[j]);
                const bool sp = (v[j] - 1.0f) >= 0.0f;
                svp[j] = sp ? 1 : 0;
                if (sp) v[j] = 0.f;
            }
            *reinterpret_cast<uchar4*>(
                &s1[(size_t)((t * BN_) + bn0 + i0 + i) * H_ + h0 + j0]) = sv;
        }
    }
}

// ---------------- Kernel 2: y = s1 @ W2^T (NT gemm, K=2048, A is u8 spikes),
// ---------------- fused PLIF scan over T, write fp32 spikes to d_out.
__global__ __launch_bounds__(256)
void k_fc2_scan(const unsigned char* __restrict__ s1, const float* __restrict__ W2,
                const float* __restrict__ alpha2p, float* __restrict__ out)
{
    __shared__ float As[T_][BK][PAD];
    __shared__ float Bs[BK][PAD];

    const int tid = threadIdx.x;
    const int bn0 = blockIdx.x * BM;
    const int d0  = blockIdx.y * BNT;
    const int tx  = tid & 15, ty = tid >> 4;
    const int i0  = ty * 4, j0 = tx * 4;
    const int srow = tid >> 2;
    const int sseg = tid & 3;

    float acc[T_][4][4];
#pragma unroll
    for (int t = 0; t < T_; ++t)
#pragma unroll
        for (int i = 0; i < 4; ++i)
#pragma unroll
            for (int j = 0; j < 4; ++j) acc[t][i][j] = 0.f;

    for (int k0 = 0; k0 < H_; k0 += BK) {
#pragma unroll
        for (int t = 0; t < T_; ++t) {
            const uchar4 av = *reinterpret_cast<const uchar4*>(
                &s1[(size_t)((t * BN_) + bn0 + srow) * H_ + k0 + sseg * 4]);
            As[t][sseg * 4 + 0][srow] = (float)av.x;
            As[t][sseg * 4 + 1][srow] = (float)av.y;
            As[t][sseg * 4 + 2][srow] = (float)av.z;
            As[t][sseg * 4 + 3][srow] = (float)av.w;
        }
        {
            const f4 bv = *reinterpret_cast<const f4*>(
                &W2[(size_t)(d0 + srow) * H_ + k0 + sseg * 4]);
            Bs[sseg * 4 + 0][srow] = bv[0];
            Bs[sseg * 4 + 1][srow] = bv[1];
            Bs[sseg * 4 + 2][srow] = bv[2];
            Bs[sseg * 4 + 3][srow] = bv[3];
        }
        __syncthreads();

#pragma unroll
        for (int kk = 0; kk < BK; ++kk) {
            const f4 b = *reinterpret_cast<const f4*>(&Bs[kk][j0]);
#pragma unroll
            for (int t = 0; t < T_; ++t) {
                const f4 a = *reinterpret_cast<const f4*>(&As[t][kk][i0]);
#pragma unroll
                for (int i = 0; i < 4; ++i)
#pragma unroll
                    for (int j = 0; j < 4; ++j)
                        acc[t][i][j] = fmaf(a[i], b[j], acc[t][i][j]);
            }
        }
        __syncthreads();
    }

    const float a2 = alpha2p[0];
#pragma unroll
    for (int i = 0; i < 4; ++i) {
        float v[4] = {0.f, 0.f, 0.f, 0.f};
#pragma unroll
        for (int t = 0; t < T_; ++t) {
            f4 sv;
#pragma unroll
            for (int j = 0; j < 4; ++j) {
                v[j] = v[j] + a2 * (acc[t][i][j] - v[j]);
                const bool sp = (v[j] - 1.0f) >= 0.0f;
                sv[j] = sp ? 1.0f : 0.0f;
                if (sp) v[j] = 0.f;
            }
            *reinterpret_cast<f4*>(
                &out[(size_t)((t * BN_) + bn0 + i0 + i) * D_ + d0 + j0]) = sv;
        }
    }
}

extern "C" void kernel_launch(void* const* d_in, const int* in_sizes, int n_in,
                              void* d_out, int out_size, void* d_ws, size_t ws_size,
                              hipStream_t stream) {
    const float* x      = (const float*)d_in[0];
    const float* W1     = (const float*)d_in[1];
    const float* W2     = (const float*)d_in[2];
    const float* alpha1 = (const float*)d_in[3];
    const float* alpha2 = (const float*)d_in[4];
    float* out = (float*)d_out;
    unsigned char* s1 = (unsigned char*)d_ws;   // T_*BN_*H_ = 64 MiB of u8 spikes

    dim3 g1(BN_ / BM, H_ / BNT);   // 128 x 32
    dim3 g2(BN_ / BM, D_ / BNT);   // 128 x 8
    k_fc1_scan<<<g1, dim3(256), 0, stream>>>(x, W1, alpha1, s1);
    k_fc2_scan<<<g2, dim3(256), 0, stream>>>(s1, W2, alpha2, out);
}

// Round 2
// 485.625 us; speedup vs baseline: 3.0712x; 3.0712x over previous
//
#include <hip/hip_runtime.h>

#define T_  4
#define BN_ 8192
#define D_  512
#define H_  2048

typedef float f4 __attribute__((ext_vector_type(4)));
typedef float f32x4 __attribute__((ext_vector_type(4)));
typedef _Float16 f16x8 __attribute__((ext_vector_type(8)));

// Split 16 consecutive fp32 into hi/lo fp16 pairs (hi = RN(v), lo = RN(v - hi)).
// v - (float)hi is Sterbenz-exact; hi+lo reconstructs v to ~2^-24 rel.
__device__ __forceinline__ void split16(const float* __restrict__ p,
                                        f16x8& h_lo, f16x8& h_hi,
                                        f16x8& l_lo, f16x8& l_hi)
{
    const f4 u0 = *(const f4*)(p);
    const f4 u1 = *(const f4*)(p + 4);
    const f4 u2 = *(const f4*)(p + 8);
    const f4 u3 = *(const f4*)(p + 12);
#pragma unroll
    for (int i = 0; i < 4; ++i) {
        _Float16 a;
        a = (_Float16)u0[i]; h_lo[i]     = a; l_lo[i]     = (_Float16)(u0[i] - (float)a);
        a = (_Float16)u1[i]; h_lo[4 + i] = a; l_lo[4 + i] = (_Float16)(u1[i] - (float)a);
        a = (_Float16)u2[i]; h_hi[i]     = a; l_hi[i]     = (_Float16)(u2[i] - (float)a);
        a = (_Float16)u3[i]; h_hi[4 + i] = a; l_hi[4 + i] = (_Float16)(u3[i] - (float)a);
    }
}

// ---------------------------------------------------------------------------
// fc1: h = x @ W1^T (M=8192/t, N=2048, K=512), 3-product f16 split GEMM,
// t-outer loop with persistent membrane state, fused PLIF scan, u8 spikes out.
// ---------------------------------------------------------------------------
__global__ __launch_bounds__(256, 2)
void k_fc1(const float* __restrict__ x, const float* __restrict__ W1,
           const float* __restrict__ alphap, unsigned char* __restrict__ s1)
{
    __shared__ _Float16 As[2][128][32];   // [split][row][k]
    __shared__ _Float16 Bs[2][128][32];

    const int tid  = threadIdx.x;
    const int lane = tid & 63;
    const int wid  = tid >> 6;
    const int wr   = (wid >> 1) * 64;     // wave row offset in 128x128 tile
    const int wc   = (wid & 1) * 64;      // wave col offset
    const int bn0  = blockIdx.x * 128;
    const int h0   = blockIdx.y * 128;

    const int sr = tid >> 1;              // staging row 0..127
    const int sk = (tid & 1) * 16;        // staging k offset {0,16}

    const int l15 = lane & 15;
    const int lk  = (lane >> 4) * 8;      // fragment k offset
    const int lq  = (lane >> 4) * 4;      // C/D fragment row offset

    const float a1 = alphap[0];

    f32x4 vst[4][4];                      // persistent membrane potential
#pragma unroll
    for (int m = 0; m < 4; ++m)
#pragma unroll
        for (int n = 0; n < 4; ++n) vst[m][n] = (f32x4){0.f, 0.f, 0.f, 0.f};

    for (int t = 0; t < T_; ++t) {
        f32x4 acc[4][4];
#pragma unroll
        for (int m = 0; m < 4; ++m)
#pragma unroll
            for (int n = 0; n < 4; ++n) acc[m][n] = (f32x4){0.f, 0.f, 0.f, 0.f};

        const float* xA = x  + (size_t)(t * BN_ + bn0 + sr) * D_ + sk;
        const float* xB = W1 + (size_t)(h0 + sr) * D_ + sk;

        for (int k0 = 0; k0 < D_; k0 += 32) {
            __syncthreads();   // protect previous iteration's reads
            {
                f16x8 hlo, hhi, llo, lhi;
                split16(xA + k0, hlo, hhi, llo, lhi);
                *(f16x8*)&As[0][sr][sk]     = hlo;
                *(f16x8*)&As[0][sr][sk + 8] = hhi;
                *(f16x8*)&As[1][sr][sk]     = llo;
                *(f16x8*)&As[1][sr][sk + 8] = lhi;

                split16(xB + k0, hlo, hhi, llo, lhi);
                *(f16x8*)&Bs[0][sr][sk]     = hlo;
                *(f16x8*)&Bs[0][sr][sk + 8] = hhi;
                *(f16x8*)&Bs[1][sr][sk]     = llo;
                *(f16x8*)&Bs[1][sr][sk + 8] = lhi;
            }
            __syncthreads();

            f16x8 a1f[4], a2f[4], b1f[4], b2f[4];
#pragma unroll
            for (int m = 0; m < 4; ++m) {
                a1f[m] = *(const f16x8*)&As[0][wr + m * 16 + l15][lk];
                a2f[m] = *(const f16x8*)&As[1][wr + m * 16 + l15][lk];
            }
#pragma unroll
            for (int n = 0; n < 4; ++n) {
                b1f[n] = *(const f16x8*)&Bs[0][wc + n * 16 + l15][lk];
                b2f[n] = *(const f16x8*)&Bs[1][wc + n * 16 + l15][lk];
            }
#pragma unroll
            for (int m = 0; m < 4; ++m)
#pragma unroll
                for (int n = 0; n < 4; ++n) {
                    acc[m][n] = __builtin_amdgcn_mfma_f32_16x16x32_f16(a1f[m], b1f[n], acc[m][n], 0, 0, 0);
                    acc[m][n] = __builtin_amdgcn_mfma_f32_16x16x32_f16(a1f[m], b2f[n], acc[m][n], 0, 0, 0);
                    acc[m][n] = __builtin_amdgcn_mfma_f32_16x16x32_f16(a2f[m], b1f[n], acc[m][n], 0, 0, 0);
                }
        }

        // PLIF scan step for this t, write u8 spikes
        unsigned char* s1t = s1 + (size_t)(t * BN_) * H_;
#pragma unroll
        for (int m = 0; m < 4; ++m) {
            const int row0 = bn0 + wr + m * 16 + lq;
#pragma unroll
            for (int n = 0; n < 4; ++n) {
                const int col = h0 + wc + n * 16 + l15;
#pragma unroll
                for (int q = 0; q < 4; ++q) {
                    float v = vst[m][n][q];
                    v = v + a1 * (acc[m][n][q] - v);
                    const bool sp = (v >= 1.0f);
                    s1t[(size_t)(row0 + q) * H_ + col] = sp ? (unsigned char)1 : (unsigned char)0;
                    vst[m][n][q] = sp ? 0.0f : v;
                }
            }
        }
    }
}

// ---------------------------------------------------------------------------
// fc2: y = s1 @ W2^T (M=8192/t, N=512, K=2048). A = binary spikes (exact f16,
// no split); B = W2 2-way f16 split -> 2 products. Fused PLIF scan, f32 out.
// Tile 128(M) x 64(N), 4 waves of 64x32.
// ---------------------------------------------------------------------------
__global__ __launch_bounds__(256, 2)
void k_fc2(const unsigned char* __restrict__ s1, const float* __restrict__ W2,
           const float* __restrict__ alphap, float* __restrict__ out)
{
    __shared__ _Float16 As[128][32];
    __shared__ _Float16 Bs[2][64][32];

    const int tid  = threadIdx.x;
    const int lane = tid & 63;
    const int wid  = tid >> 6;
    const int wr   = (wid >> 1) * 64;     // {0,64}
    const int wc   = (wid & 1) * 32;      // {0,32}
    const int bn0  = blockIdx.x * 128;
    const int d0   = blockIdx.y * 64;

    const int sr = tid >> 1;
    const int sk = (tid & 1) * 16;

    const int l15 = lane & 15;
    const int lk  = (lane >> 4) * 8;
    const int lq  = (lane >> 4) * 4;

    const float a2 = alphap[0];

    f32x4 vst[4][2];
#pragma unroll
    for (int m = 0; m < 4; ++m)
#pragma unroll
        for (int n = 0; n < 2; ++n) vst[m][n] = (f32x4){0.f, 0.f, 0.f, 0.f};

    for (int t = 0; t < T_; ++t) {
        f32x4 acc[4][2];
#pragma unroll
        for (int m = 0; m < 4; ++m)
#pragma unroll
            for (int n = 0; n < 2; ++n) acc[m][n] = (f32x4){0.f, 0.f, 0.f, 0.f};

        const unsigned char* pA = s1 + (size_t)(t * BN_ + bn0 + sr) * H_ + sk;
        const float*         pB = W2 + (size_t)(d0 + (tid >> 1)) * H_ + sk;

        for (int k0 = 0; k0 < H_; k0 += 32) {
            __syncthreads();
            {   // stage A: 16 u8 spikes -> f16
                const uint4 raw = *(const uint4*)(pA + k0);
                f16x8 lo, hi;
#pragma unroll
                for (int i = 0; i < 4; ++i) {
                    lo[i]     = (_Float16)((raw.x >> (8 * i)) & 0xFFu);
                    lo[4 + i] = (_Float16)((raw.y >> (8 * i)) & 0xFFu);
                    hi[i]     = (_Float16)((raw.z >> (8 * i)) & 0xFFu);
                    hi[4 + i] = (_Float16)((raw.w >> (8 * i)) & 0xFFu);
                }
                *(f16x8*)&As[sr][sk]     = lo;
                *(f16x8*)&As[sr][sk + 8] = hi;
            }
            if (tid < 128) {   // stage B: 64 rows of W2, split
                f16x8 hlo, hhi, llo, lhi;
                split16(pB + k0, hlo, hhi, llo, lhi);
                const int r = tid >> 1;
                *(f16x8*)&Bs[0][r][sk]     = hlo;
                *(f16x8*)&Bs[0][r][sk + 8] = hhi;
                *(f16x8*)&Bs[1][r][sk]     = llo;
                *(f16x8*)&Bs[1][r][sk + 8] = lhi;
            }
            __syncthreads();

            f16x8 af[4], b1f[2], b2f[2];
#pragma unroll
            for (int m = 0; m < 4; ++m)
                af[m] = *(const f16x8*)&As[wr + m * 16 + l15][lk];
#pragma unroll
            for (int n = 0; n < 2; ++n) {
                b1f[n] = *(const f16x8*)&Bs[0][wc + n * 16 + l15][lk];
                b2f[n] = *(const f16x8*)&Bs[1][wc + n * 16 + l15][lk];
            }
#pragma unroll
            for (int m = 0; m < 4; ++m)
#pragma unroll
                for (int n = 0; n < 2; ++n) {
                    acc[m][n] = __builtin_amdgcn_mfma_f32_16x16x32_f16(af[m], b1f[n], acc[m][n], 0, 0, 0);
                    acc[m][n] = __builtin_amdgcn_mfma_f32_16x16x32_f16(af[m], b2f[n], acc[m][n], 0, 0, 0);
                }
        }

        float* outt = out + (size_t)(t * BN_) * D_;
#pragma unroll
        for (int m = 0; m < 4; ++m) {
            const int row0 = bn0 + wr + m * 16 + lq;
#pragma unroll
            for (int n = 0; n < 2; ++n) {
                const int col = d0 + wc + n * 16 + l15;
#pragma unroll
                for (int q = 0; q < 4; ++q) {
                    float v = vst[m][n][q];
                    v = v + a2 * (acc[m][n][q] - v);
                    const bool sp = (v >= 1.0f);
                    outt[(size_t)(row0 + q) * D_ + col] = sp ? 1.0f : 0.0f;
                    vst[m][n][q] = sp ? 0.0f : v;
                }
            }
        }
    }
}

extern "C" void kernel_launch(void* const* d_in, const int* in_sizes, int n_in,
                              void* d_out, int out_size, void* d_ws, size_t ws_size,
                              hipStream_t stream) {
    const float* x      = (const float*)d_in[0];
    const float* W1     = (const float*)d_in[1];
    const float* W2     = (const float*)d_in[2];
    const float* alpha1 = (const float*)d_in[3];
    const float* alpha2 = (const float*)d_in[4];
    float* out = (float*)d_out;
    unsigned char* s1 = (unsigned char*)d_ws;   // [T][BN][H] u8 = 64 MiB

    dim3 g1(BN_ / 128, H_ / 128);   // 64 x 16
    dim3 g2(BN_ / 128, D_ / 64);    // 64 x 8
    k_fc1<<<g1, dim3(256), 0, stream>>>(x, W1, alpha1, s1);
    k_fc2<<<g2, dim3(256), 0, stream>>>(s1, W2, alpha2, out);
}

// Round 3
// 381.129 us; speedup vs baseline: 3.9133x; 1.2742x over previous
//
#include <hip/hip_runtime.h>

#define T_  4
#define BN_ 8192
#define D_  512
#define H_  2048
#define LDK 40   // padded LDS row length in f16 (80 B stride -> conflict-free-ish)

typedef float f4 __attribute__((ext_vector_type(4)));
typedef float f32x4 __attribute__((ext_vector_type(4)));
typedef _Float16 f16x8 __attribute__((ext_vector_type(8)));

// Split 16 consecutive fp32 into hi/lo fp16 pairs (hi = RN(v), lo = RN(v - hi)).
__device__ __forceinline__ void split16(const float* __restrict__ p,
                                        f16x8& h_lo, f16x8& h_hi,
                                        f16x8& l_lo, f16x8& l_hi)
{
    const f4 u0 = *(const f4*)(p);
    const f4 u1 = *(const f4*)(p + 4);
    const f4 u2 = *(const f4*)(p + 8);
    const f4 u3 = *(const f4*)(p + 12);
#pragma unroll
    for (int i = 0; i < 4; ++i) {
        _Float16 a;
        a = (_Float16)u0[i]; h_lo[i]     = a; l_lo[i]     = (_Float16)(u0[i] - (float)a);
        a = (_Float16)u1[i]; h_lo[4 + i] = a; l_lo[4 + i] = (_Float16)(u1[i] - (float)a);
        a = (_Float16)u2[i]; h_hi[i]     = a; l_hi[i]     = (_Float16)(u2[i] - (float)a);
        a = (_Float16)u3[i]; h_hi[4 + i] = a; l_hi[4 + i] = (_Float16)(u3[i] - (float)a);
    }
}

// 4 spike bytes (each 0/1) -> 4 packed f16 (two u32s). Exact: lanes <=1, 0x3C00*1 fits u16.
__device__ __forceinline__ void spikes4_to_f16(unsigned b, unsigned& lo, unsigned& hi)
{
    const unsigned p0 = (b & 0xFFu) | ((b & 0xFF00u) << 8);          // u16 lanes (b1,b0)
    const unsigned p1 = ((b >> 16) & 0xFFu) | ((b >> 8) & 0xFF0000u); // u16 lanes (b3,b2)
    lo = p0 * 0x3C00u;
    hi = p1 * 0x3C00u;
}

// ---------------------------------------------------------------------------
// fc1: h = x @ W1^T (per t: M=8192, N=2048, K=512), 3-product f16 split GEMM,
// t-outer loop, persistent membrane state, fused PLIF, u8 spikes to ws.
// ---------------------------------------------------------------------------
__global__ __launch_bounds__(256, 2)
void k_fc1(const float* __restrict__ x, const float* __restrict__ W1,
           const float* __restrict__ alphap, unsigned char* __restrict__ s1)
{
    __shared__ __align__(16) _Float16 As[2][128][LDK];
    __shared__ __align__(16) _Float16 Bs[2][128][LDK];

    const int tid  = threadIdx.x;
    const int lane = tid & 63;
    const int wid  = tid >> 6;
    const int wr   = (wid >> 1) * 64;
    const int wc   = (wid & 1) * 64;
    const int bn0  = blockIdx.x * 128;
    const int h0   = blockIdx.y * 128;

    const int sr = tid >> 1;
    const int sk = (tid & 1) * 16;

    const int l15 = lane & 15;
    const int lk  = (lane >> 4) * 8;
    const int lq  = (lane >> 4) * 4;

    const float a1 = alphap[0];

    f32x4 vst[4][4];
#pragma unroll
    for (int m = 0; m < 4; ++m)
#pragma unroll
        for (int n = 0; n < 4; ++n) vst[m][n] = (f32x4){0.f, 0.f, 0.f, 0.f};

    for (int t = 0; t < T_; ++t) {
        f32x4 acc[4][4];
#pragma unroll
        for (int m = 0; m < 4; ++m)
#pragma unroll
            for (int n = 0; n < 4; ++n) acc[m][n] = (f32x4){0.f, 0.f, 0.f, 0.f};

        const float* xA = x  + (size_t)(t * BN_ + bn0 + sr) * D_ + sk;
        const float* xB = W1 + (size_t)(h0 + sr) * D_ + sk;

        for (int k0 = 0; k0 < D_; k0 += 32) {
            __syncthreads();
            {
                f16x8 hlo, hhi, llo, lhi;
                split16(xA + k0, hlo, hhi, llo, lhi);
                *(f16x8*)&As[0][sr][sk]     = hlo;
                *(f16x8*)&As[0][sr][sk + 8] = hhi;
                *(f16x8*)&As[1][sr][sk]     = llo;
                *(f16x8*)&As[1][sr][sk + 8] = lhi;

                split16(xB + k0, hlo, hhi, llo, lhi);
                *(f16x8*)&Bs[0][sr][sk]     = hlo;
                *(f16x8*)&Bs[0][sr][sk + 8] = hhi;
                *(f16x8*)&Bs[1][sr][sk]     = llo;
                *(f16x8*)&Bs[1][sr][sk + 8] = lhi;
            }
            __syncthreads();

            f16x8 a1f[4], a2f[4], b1f[4], b2f[4];
#pragma unroll
            for (int m = 0; m < 4; ++m) {
                a1f[m] = *(const f16x8*)&As[0][wr + m * 16 + l15][lk];
                a2f[m] = *(const f16x8*)&As[1][wr + m * 16 + l15][lk];
            }
#pragma unroll
            for (int n = 0; n < 4; ++n) {
                b1f[n] = *(const f16x8*)&Bs[0][wc + n * 16 + l15][lk];
                b2f[n] = *(const f16x8*)&Bs[1][wc + n * 16 + l15][lk];
            }
#pragma unroll
            for (int m = 0; m < 4; ++m)
#pragma unroll
                for (int n = 0; n < 4; ++n) {
                    acc[m][n] = __builtin_amdgcn_mfma_f32_16x16x32_f16(a1f[m], b1f[n], acc[m][n], 0, 0, 0);
                    acc[m][n] = __builtin_amdgcn_mfma_f32_16x16x32_f16(a1f[m], b2f[n], acc[m][n], 0, 0, 0);
                    acc[m][n] = __builtin_amdgcn_mfma_f32_16x16x32_f16(a2f[m], b1f[n], acc[m][n], 0, 0, 0);
                }
        }

        unsigned char* s1t = s1 + (size_t)(t * BN_) * H_;
#pragma unroll
        for (int m = 0; m < 4; ++m) {
            const int row0 = bn0 + wr + m * 16 + lq;
#pragma unroll
            for (int n = 0; n < 4; ++n) {
                const int col = h0 + wc + n * 16 + l15;
#pragma unroll
                for (int q = 0; q < 4; ++q) {
                    float v = vst[m][n][q];
                    v = v + a1 * (acc[m][n][q] - v);
                    const bool sp = (v >= 1.0f);
                    s1t[(size_t)(row0 + q) * H_ + col] = sp ? (unsigned char)1 : (unsigned char)0;
                    vst[m][n][q] = sp ? 0.0f : v;
                }
            }
        }
    }
}

// ---------------------------------------------------------------------------
// fc2: y = s1 @ W2^T (M=8192, N=512, K=2048), ALL 4 timesteps fused in one
// K-loop (B tile shared across t -> 4x MFMA per barrier). A = binary spikes
// (exact f16); B = W2 2-way split. PLIF scan at the end, f32 spikes to d_out.
// ---------------------------------------------------------------------------
__global__ __launch_bounds__(256, 2)
void k_fc2(const unsigned char* __restrict__ s1, const float* __restrict__ W2,
           const float* __restrict__ alphap, float* __restrict__ out)
{
    __shared__ __align__(16) _Float16 As[T_][128][LDK];
    __shared__ __align__(16) _Float16 Bs[2][64][LDK];

    const int tid  = threadIdx.x;
    const int lane = tid & 63;
    const int wid  = tid >> 6;
    const int wr   = (wid >> 1) * 64;     // {0,64}
    const int wc   = (wid & 1) * 32;      // {0,32}
    const int bn0  = blockIdx.x * 128;
    const int d0   = blockIdx.y * 64;

    const int sr = tid >> 1;
    const int sk = (tid & 1) * 16;

    const int l15 = lane & 15;
    const int lk  = (lane >> 4) * 8;
    const int lq  = (lane >> 4) * 4;

    const float a2 = alphap[0];

    f32x4 acc[T_][4][2];
#pragma unroll
    for (int t = 0; t < T_; ++t)
#pragma unroll
        for (int m = 0; m < 4; ++m)
#pragma unroll
            for (int n = 0; n < 2; ++n) acc[t][m][n] = (f32x4){0.f, 0.f, 0.f, 0.f};

    const unsigned char* pA = s1 + (size_t)(bn0 + sr) * H_ + sk;
    const float*         pB = W2 + (size_t)(d0 + sr) * H_ + sk;   // valid for tid<128

    for (int k0 = 0; k0 < H_; k0 += 32) {
        __syncthreads();
#pragma unroll
        for (int t = 0; t < T_; ++t) {
            const uint4 raw = *(const uint4*)(pA + (size_t)t * ((size_t)BN_ * H_) + k0);
            unsigned w[8];
            spikes4_to_f16(raw.x, w[0], w[1]);
            spikes4_to_f16(raw.y, w[2], w[3]);
            spikes4_to_f16(raw.z, w[4], w[5]);
            spikes4_to_f16(raw.w, w[6], w[7]);
            *(uint4*)&As[t][sr][sk]     = *(const uint4*)&w[0];
            *(uint4*)&As[t][sr][sk + 8] = *(const uint4*)&w[4];
        }
        if (tid < 128) {
            f16x8 hlo, hhi, llo, lhi;
            split16(pB + k0, hlo, hhi, llo, lhi);
            const int r = tid >> 1;
            *(f16x8*)&Bs[0][r][sk]     = hlo;
            *(f16x8*)&Bs[0][r][sk + 8] = hhi;
            *(f16x8*)&Bs[1][r][sk]     = llo;
            *(f16x8*)&Bs[1][r][sk + 8] = lhi;
        }
        __syncthreads();

        f16x8 b1f[2], b2f[2];
#pragma unroll
        for (int n = 0; n < 2; ++n) {
            b1f[n] = *(const f16x8*)&Bs[0][wc + n * 16 + l15][lk];
            b2f[n] = *(const f16x8*)&Bs[1][wc + n * 16 + l15][lk];
        }
#pragma unroll
        for (int t = 0; t < T_; ++t) {
            f16x8 af[4];
#pragma unroll
            for (int m = 0; m < 4; ++m)
                af[m] = *(const f16x8*)&As[t][wr + m * 16 + l15][lk];
#pragma unroll
            for (int m = 0; m < 4; ++m)
#pragma unroll
                for (int n = 0; n < 2; ++n) {
                    acc[t][m][n] = __builtin_amdgcn_mfma_f32_16x16x32_f16(af[m], b1f[n], acc[t][m][n], 0, 0, 0);
                    acc[t][m][n] = __builtin_amdgcn_mfma_f32_16x16x32_f16(af[m], b2f[n], acc[t][m][n], 0, 0, 0);
                }
        }
    }

    // PLIF scan over t (sequential), write f32 spikes
#pragma unroll
    for (int m = 0; m < 4; ++m) {
        const int row0 = bn0 + wr + m * 16 + lq;
#pragma unroll
        for (int n = 0; n < 2; ++n) {
            const int col = d0 + wc + n * 16 + l15;
#pragma unroll
            for (int q = 0; q < 4; ++q) {
                float v = 0.f;
#pragma unroll
                for (int t = 0; t < T_; ++t) {
                    v = v + a2 * (acc[t][m][n][q] - v);
                    const bool sp = (v >= 1.0f);
                    out[(size_t)(t * BN_ + row0 + q) * D_ + col] = sp ? 1.0f : 0.0f;
                    if (sp) v = 0.f;
                }
            }
        }
    }
}

extern "C" void kernel_launch(void* const* d_in, const int* in_sizes, int n_in,
                              void* d_out, int out_size, void* d_ws, size_t ws_size,
                              hipStream_t stream) {
    const float* x      = (const float*)d_in[0];
    const float* W1     = (const float*)d_in[1];
    const float* W2     = (const float*)d_in[2];
    const float* alpha1 = (const float*)d_in[3];
    const float* alpha2 = (const float*)d_in[4];
    float* out = (float*)d_out;
    unsigned char* s1 = (unsigned char*)d_ws;   // [T][BN][H] u8 = 64 MiB

    dim3 g1(BN_ / 128, H_ / 128);   // 64 x 16
    dim3 g2(BN_ / 128, D_ / 64);    // 64 x 8
    k_fc1<<<g1, dim3(256), 0, stream>>>(x, W1, alpha1, s1);
    k_fc2<<<g2, dim3(256), 0, stream>>>(s1, W2, alpha2, out);
}